// Round 11
// baseline (15.752 us; speedup 1.0000x reference)
//
#include <hip/hip_runtime.h>

// Problem constants (from reference)
#define N_ 16
#define A_ 4096
#define G_ 256
#define C_ 80
#define BIG_ 1e8f
#define LN2_ 0.69314718055994531f

// Round 11: chain-shortening + VMEM compression on the round-10 structure.
//  - logits loaded as dwordx4+dword (lane owns classes [5sub,5sub+5), 20B
//    contiguous per lane, 320B coalesced per group): 5 -> 2 VMEM insts/pass
//  - (g<<8)|cls packed into the argmin key: u64 (d_bits<<32)|meta reduced
//    with 4 DPP stages. u64 min = lexicographic (d, g) = exact
//    first-occurrence jnp.argmin; target available with zero extra latency
//    (the dependent s_cls LDS broadcast is gone)
//  - s_gt[closest] (for proj) issued before the focal trans chain: its
//    ~120cyc LDS latency hides under exp/log/rcp
// Masked-out gt boxes staged as (BIG,...): never win; nonempty <=> dmin<BIG.

#define DPP_XOR1  0xB1   // quad_perm(1,0,3,2)
#define DPP_XOR2  0x4E   // quad_perm(2,3,0,1)
#define DPP_XOR7  0x141  // row_half_mirror
#define DPP_XOR15 0x140  // row_mirror

template<int CTRL>
__device__ __forceinline__ int dppi(int x) {
    return __builtin_amdgcn_update_dpp(0, x, CTRL, 0xF, 0xF, true);
}
template<int CTRL>
__device__ __forceinline__ float dppf(float x) {
    return __int_as_float(dppi<CTRL>(__float_as_int(x)));
}
// one u64-key butterfly stage: key = min(key, partner_key)
template<int CTRL>
__device__ __forceinline__ void kmin_stage(unsigned long long& key) {
    const unsigned lo = (unsigned)dppi<CTRL>((int)(unsigned)key);
    const unsigned hi = (unsigned)dppi<CTRL>((int)(unsigned)(key >> 32));
    const unsigned long long o = ((unsigned long long)hi << 32) | lo;
    key = (o < key) ? o : key;
}

typedef float f4a4 __attribute__((ext_vector_type(4), aligned(4)));

__global__ __launch_bounds__(256, 4) void cbppl_fused_kernel(
    const float* __restrict__ gt_padded,    // (N, G, 4)
    const float* __restrict__ prop_boxes,   // (N, A, 4)
    const float* __restrict__ pred_boxes,   // (N, A, 4)
    const float* __restrict__ class_logits, // (N, A, C)
    const int*   __restrict__ gt_masks,     // (N, G) bool->int32
    const int*   __restrict__ gt_classes,   // (N, G)
    float* __restrict__ out_cls,            // (N, A)
    float* __restrict__ out_proj)           // (N, A)
{
    __shared__ float4 s_gt[G_];
    __shared__ int    s_meta[G_];   // (g<<8) | cls[g]

    const int t   = threadIdx.x;
    const int sub = t & 15;                 // lane-in-group
    const int n   = blockIdx.x >> 6;        // 64 blocks per batch
    const int ab  = (blockIdx.x & 63) << 6; // 64 anchors per block

    // ---- one-time: stage masked gt boxes + packed meta to LDS ----
    {
        const int gidx = n * G_ + t;        // t == g (256 threads)
        float4 g4 = ((const float4*)gt_padded)[gidx];
        if (!gt_masks[gidx]) { g4.x = BIG_; g4.y = BIG_; g4.z = BIG_; g4.w = BIG_; }
        s_gt[t]   = g4;
        s_meta[t] = (t << 8) | gt_classes[gidx];
    }
    __syncthreads();

    // ---- one-time: register-cache 16 boxes + meta per lane ----
    float4 b[16];
    int    meta[16];
    #pragma unroll
    for (int m = 0; m < 16; ++m) {
        b[m]    = s_gt[sub + (m << 4)];
        meta[m] = s_meta[sub + (m << 4)];
    }

    // ---- 4 passes: 4 anchors per pass (one per 16-lane group) ----
    for (int p = 0; p < 4; ++p) {
        const int ai  = ((t >> 6) << 4) + (p << 2) + ((t >> 4) & 3);
        const int row = n * A_ + ab + ai;

        const float4 pb = ((const float4*)prop_boxes)[row];   // group-broadcast
        const float4 qb = ((const float4*)pred_boxes)[row];

        // logits: 20B contiguous per lane -> dwordx4 + dword (2 VMEM insts)
        const float* lrow = class_logits + (size_t)row * C_ + sub * 5;
        const f4a4  x4  = *(const f4a4*)lrow;
        const float x4v = lrow[4];

        // local argmin over 16 register boxes, meta rides along
        float dloc = INFINITY;
        int   mt   = 0;
        #pragma unroll
        for (int m = 0; m < 16; ++m) {
            const float d = fabsf(pb.x - b[m].x) + fabsf(pb.y - b[m].y)
                          + fabsf(pb.z - b[m].z) + fabsf(pb.w - b[m].w);
            if (d < dloc) { dloc = d; mt = meta[m]; }  // lower m = lower g
        }

        // 16-lane argmin as u64-key DPP butterfly (VALU pipe only):
        // key = (d_bits<<32)|(g<<8)|cls ; min = (min d, then min g) exact
        unsigned long long key =
            ((unsigned long long)__float_as_uint(dloc) << 32) | (unsigned)mt;
        kmin_stage<DPP_XOR1 >(key);
        kmin_stage<DPP_XOR2 >(key);
        kmin_stage<DPP_XOR7 >(key);
        kmin_stage<DPP_XOR15>(key);

        const int   target   = (int)(key & 0xFF);          // cls of winner
        const int   closest  = (int)((key >> 8) & 0xFF);   // g of winner
        const float dmin     = __uint_as_float((unsigned)(key >> 32));
        const int   nonempty = (dmin < BIG_);

        // proj lookup issued NOW; its LDS latency hides under the focal math
        const float4 cb = s_gt[closest];

        // focal, negative-class closed form (branchless; exact identities):
        //   u = e^-x;  p = 1/(1+u);  softplus = x + ln2*log2(1+u)
        const float xs[5] = {x4.x, x4.y, x4.z, x4.w, x4v};
        float acc = 0.0f;
        #pragma unroll
        for (int j = 0; j < 5; ++j) {
            const float x  = xs[j];
            const float u  = __expf(-x);
            const float tt = 1.0f + u;
            const float sp = fmaf(LN2_, __log2f(tt), x);
            const float r  = __builtin_amdgcn_rcpf(tt);
            acc = fmaf(sp, r * r, acc);
        }
        acc *= 0.75f;

        // target-class correction; owner lane iff 0 <= rel < 5
        {
            const int rel = target - sub * 5;
            float xt = xs[0];
            xt = (rel == 1) ? xs[1] : xt;
            xt = (rel == 2) ? xs[2] : xt;
            xt = (rel == 3) ? xs[3] : xt;
            xt = (rel == 4) ? xs[4] : xt;
            const float u  = __expf(-xt);
            const float tt = 1.0f + u;
            const float sp = fmaf(LN2_, __log2f(tt), xt);
            const float pp = __builtin_amdgcn_rcpf(tt);
            const float q  = 1.0f - pp;
            const float corr = fmaf(0.25f * (sp - xt), q * q,
                                    -0.75f * sp * pp * pp);
            acc += ((unsigned)rel < 5u) ? corr : 0.0f;
        }

        // group sum of focal partials on DPP
        acc += dppf<DPP_XOR1 >(acc);
        acc += dppf<DPP_XOR2 >(acc);
        acc += dppf<DPP_XOR7 >(acc);
        acc += dppf<DPP_XOR15>(acc);

        const float pd = fabsf(qb.x - cb.x) + fabsf(qb.y - cb.y)
                       + fabsf(qb.z - cb.z) + fabsf(qb.w - cb.w);

        if (sub == 0) {
            out_cls[row]  = nonempty ? acc * (1.0f / (float)C_) : 0.0f;
            out_proj[row] = nonempty ? pd : 0.0f;
        }
    }
}

extern "C" void kernel_launch(void* const* d_in, const int* in_sizes, int n_in,
                              void* d_out, int out_size, void* d_ws, size_t ws_size,
                              hipStream_t stream) {
    const float* gt_padded    = (const float*)d_in[0];
    const float* prop_boxes   = (const float*)d_in[1];
    const float* pred_boxes   = (const float*)d_in[2];
    const float* class_logits = (const float*)d_in[3];
    const int*   gt_masks     = (const int*)d_in[4];
    const int*   gt_classes   = (const int*)d_in[5];

    float* out = (float*)d_out;
    float* out_cls  = out;             // classification_loss, (N, A)
    float* out_proj = out + N_ * A_;   // projection_loss,     (N, A)

    dim3 grid(N_ * A_ / 64);           // 1024 blocks, 64 anchors each
    dim3 block(256);
    cbppl_fused_kernel<<<grid, block, 0, stream>>>(
        gt_padded, prop_boxes, pred_boxes, class_logits,
        gt_masks, gt_classes, out_cls, out_proj);
}